// Round 4
// baseline (7799.137 us; speedup 1.0000x reference)
//
#include <hip/hip_runtime.h>
#include <hip/hip_bf16.h>
#include <math.h>

#define T_STEPS 1024
#define HDIM    1024
#define SDIM    4096
#define NBLK    256

// fast transcendentals (v_exp_f32 + v_rcp_f32); |err| ~1e-6, fine vs 2.7e-2 thr
__device__ __forceinline__ float sigmoid_f(float x) {
    return __builtin_amdgcn_rcpf(1.0f + __expf(-x));
}
__device__ __forceinline__ float tanh_f(float x) {
    // 1 - 2/(e^{2x}+1); saturates correctly at +/-inf
    return 1.0f - 2.0f * __builtin_amdgcn_rcpf(1.0f + __expf(2.0f * x));
}

// ---------------------------------------------------------------------------
// GEMM: C[M][N] = X[M][K] @ W[N][K]^T + (b1[N] + b2[N])
// 64x64 tile, BK=16, 256 threads, 4x4 register blocking.
// ---------------------------------------------------------------------------
__global__ __launch_bounds__(256) void gemm_xg(
    const float* __restrict__ X, const float* __restrict__ W,
    const float* __restrict__ b1, const float* __restrict__ b2,
    float* __restrict__ C, int M, int N, int K)
{
    __shared__ float As[16][64];
    __shared__ float Bs[16][64];
    const int tid = threadIdx.x;
    const int m0 = blockIdx.y * 64, n0 = blockIdx.x * 64;
    const int tx = tid & 15, ty = tid >> 4;
    const int lr = tid >> 2, ls = (tid & 3) << 2;
    float acc[4][4] = {};

    for (int kt = 0; kt < K; kt += 16) {
        const float4 xa = *(const float4*)(X + (size_t)(m0 + lr) * K + kt + ls);
        const float4 wb = *(const float4*)(W + (size_t)(n0 + lr) * K + kt + ls);
        __syncthreads();  // protect previous iteration's LDS reads
        As[ls + 0][lr] = xa.x; As[ls + 1][lr] = xa.y; As[ls + 2][lr] = xa.z; As[ls + 3][lr] = xa.w;
        Bs[ls + 0][lr] = wb.x; Bs[ls + 1][lr] = wb.y; Bs[ls + 2][lr] = wb.z; Bs[ls + 3][lr] = wb.w;
        __syncthreads();
#pragma unroll
        for (int k = 0; k < 16; ++k) {
            const float4 a = *(const float4*)&As[k][ty << 2];
            const float4 b = *(const float4*)&Bs[k][tx << 2];
            acc[0][0] += a.x * b.x; acc[0][1] += a.x * b.y; acc[0][2] += a.x * b.z; acc[0][3] += a.x * b.w;
            acc[1][0] += a.y * b.x; acc[1][1] += a.y * b.y; acc[1][2] += a.y * b.z; acc[1][3] += a.y * b.w;
            acc[2][0] += a.z * b.x; acc[2][1] += a.z * b.y; acc[2][2] += a.z * b.z; acc[2][3] += a.z * b.w;
            acc[3][0] += a.w * b.x; acc[3][1] += a.w * b.y; acc[3][2] += a.w * b.z; acc[3][3] += a.w * b.w;
        }
    }
    const int gn = n0 + (tx << 2);
    const float4 bias = make_float4(b1[gn + 0] + b2[gn + 0], b1[gn + 1] + b2[gn + 1],
                                    b1[gn + 2] + b2[gn + 2], b1[gn + 3] + b2[gn + 3]);
#pragma unroll
    for (int i = 0; i < 4; ++i) {
        float4 o = make_float4(acc[i][0] + bias.x, acc[i][1] + bias.y,
                               acc[i][2] + bias.z, acc[i][3] + bias.w);
        *(float4*)(C + (size_t)(m0 + (ty << 2) + i) * N + gn) = o;
    }
}

// force a float4 to live in VGPRs; asm-defined values cannot be
// rematerialized-from-memory by the register allocator
#define PIN4(v) asm volatile("" : "+v"(v.x), "+v"(v.y), "+v"(v.z), "+v"(v.w))

// ---------------------------------------------------------------------------
// Persistent LSTM scan, v4.
//  - Fused data+flag u64 publish into 2-row rotating tagbuf (see v3 notes;
//    race-free: row r only overwritten after all consumers done with it,
//    LDS copy uses the very registers that passed the tag check).
//  - ALL 256 threads poll (4 tags each) -> low reg pressure in hot path,
//    h broadcast to LDS directly from polled registers.
//  - Weights PINNED in VGPRs via empty asm (v3 had VGPR=72: RA rematerialized
//    the 64 weight loads inside the loop -> 16 L1-thrashing loads/step on the
//    serial chain).
//  - Fast sigmoid/tanh (v_exp + v_rcp) on the recurrence path.
// ---------------------------------------------------------------------------
__global__ __launch_bounds__(256, 1) void lstm_scan(
    const float* __restrict__ xg,     // [T][4H], bias already added
    const float* __restrict__ w_hh,   // [4H][H]
    const float* __restrict__ h0, const float* __restrict__ c0,
    float* __restrict__ ys,           // [T][H] plain output (gemm/out1 input)
    float* __restrict__ hN, float* __restrict__ cN,
    unsigned long long* __restrict__ tagbuf,  // [2][1024], zeroed per launch
    unsigned tag_base)
{
    __shared__ float h_lds[HDIM];
    const int tid = threadIdx.x, lane = tid & 63, wv = tid >> 6;
    const int j = (blockIdx.x << 2) + wv;   // output column owned by this wave

    const float4* r0 = (const float4*)(w_hh + (size_t)j * HDIM);
    const float4* r1 = (const float4*)(w_hh + (size_t)(j + HDIM) * HDIM);
    const float4* r2 = (const float4*)(w_hh + (size_t)(j + 2 * HDIM) * HDIM);
    const float4* r3 = (const float4*)(w_hh + (size_t)(j + 3 * HDIM) * HDIM);
    float4 w0[4], w1[4], w2[4], w3[4];
#pragma unroll
    for (int k = 0; k < 4; ++k) {
        const int idx = lane + (k << 6);
        w0[k] = r0[idx]; w1[k] = r1[idx]; w2[k] = r2[idx]; w3[k] = r3[idx];
    }
#pragma unroll
    for (int k = 0; k < 4; ++k) { PIN4(w0[k]); PIN4(w1[k]); PIN4(w2[k]); PIN4(w3[k]); }

    float c = c0[j];
    float h_out = 0.0f;

    for (int t = 0; t < T_STEPS; ++t) {
        // this step's gate biases: cached loads issued before the wait
        const float* xgt = xg + (size_t)t * (4 * HDIM);
        const float xb_i = xgt[j];
        const float xb_f = xgt[j + HDIM];
        const float xb_g = xgt[j + 2 * HDIM];
        const float xb_o = xgt[j + 3 * HDIM];

        if (t == 0) {
#pragma unroll
            for (int q = 0; q < 4; ++q)
                h_lds[tid + (q << 8)] = h0[tid + (q << 8)];
        } else {
            const unsigned long long* row = tagbuf + ((size_t)((t - 1) & 1) << 10);
            const unsigned want = tag_base + (unsigned)t;
            unsigned long long v0, v1, v2, v3;
            for (;;) {
                v0 = __hip_atomic_load(row + tid,       __ATOMIC_RELAXED, __HIP_MEMORY_SCOPE_AGENT);
                v1 = __hip_atomic_load(row + tid + 256, __ATOMIC_RELAXED, __HIP_MEMORY_SCOPE_AGENT);
                v2 = __hip_atomic_load(row + tid + 512, __ATOMIC_RELAXED, __HIP_MEMORY_SCOPE_AGENT);
                v3 = __hip_atomic_load(row + tid + 768, __ATOMIC_RELAXED, __HIP_MEMORY_SCOPE_AGENT);
                const bool ok = ((unsigned)(v0 >> 32) == want) & ((unsigned)(v1 >> 32) == want) &
                                ((unsigned)(v2 >> 32) == want) & ((unsigned)(v3 >> 32) == want);
                if (ok) break;
            }
            union { unsigned u; float f; } c0_, c1_, c2_, c3_;
            c0_.u = (unsigned)v0; c1_.u = (unsigned)v1; c2_.u = (unsigned)v2; c3_.u = (unsigned)v3;
            h_lds[tid]       = c0_.f;
            h_lds[tid + 256] = c1_.f;
            h_lds[tid + 512] = c2_.f;
            h_lds[tid + 768] = c3_.f;
        }
        __syncthreads();   // h_lds[t] ready (also orders prior-step LDS reads)

        float gi = 0.f, gf = 0.f, gg = 0.f, go = 0.f;
#pragma unroll
        for (int k = 0; k < 4; ++k) {
            const float4 hv = *(const float4*)&h_lds[4 * (lane + (k << 6))];
            gi += w0[k].x * hv.x + w0[k].y * hv.y + w0[k].z * hv.z + w0[k].w * hv.w;
            gf += w1[k].x * hv.x + w1[k].y * hv.y + w1[k].z * hv.z + w1[k].w * hv.w;
            gg += w2[k].x * hv.x + w2[k].y * hv.y + w2[k].z * hv.z + w2[k].w * hv.w;
            go += w3[k].x * hv.x + w3[k].y * hv.y + w3[k].z * hv.z + w3[k].w * hv.w;
        }
#pragma unroll
        for (int d = 32; d > 0; d >>= 1) {
            gi += __shfl_xor(gi, d, 64);
            gf += __shfl_xor(gf, d, 64);
            gg += __shfl_xor(gg, d, 64);
            go += __shfl_xor(go, d, 64);
        }
        const float ig = sigmoid_f(gi + xb_i), fg = sigmoid_f(gf + xb_f), og = sigmoid_f(go + xb_o);
        const float gv = tanh_f(gg + xb_g);
        c = fg * c + ig * gv;
        h_out = og * tanh_f(c);

        if (lane == 0) {
            ys[(size_t)t * HDIM + j] = h_out;   // plain store (consumed post-kernel)
            union { float f; unsigned u; } hu; hu.f = h_out;
            const unsigned long long pk =
                ((unsigned long long)(tag_base + (unsigned)t + 1u) << 32) | (unsigned long long)hu.u;
            __hip_atomic_store(tagbuf + ((size_t)(t & 1) << 10) + j, pk,
                               __ATOMIC_RELAXED, __HIP_MEMORY_SCOPE_AGENT);
        }
    }
    if (lane == 0) { hN[j] = h_out; cN[j] = c; }
}

// ---------------------------------------------------------------------------
// Attention
// ---------------------------------------------------------------------------
__global__ __launch_bounds__(256) void attn_scores(
    const float* __restrict__ enc, const float* __restrict__ tgt,
    float* __restrict__ scores)
{
    const int lane = threadIdx.x & 63, wv = threadIdx.x >> 6;
    const int s = (blockIdx.x << 2) + wv;
    const float4* e4 = (const float4*)(enc + (size_t)s * HDIM);
    const float4* t4 = (const float4*)tgt;
    float acc = 0.f;
#pragma unroll
    for (int k = 0; k < 4; ++k) {
        const int idx = lane + (k << 6);
        const float4 e = e4[idx], t = t4[idx];
        acc += e.x * t.x + e.y * t.y + e.z * t.z + e.w * t.w;
    }
#pragma unroll
    for (int d = 32; d > 0; d >>= 1) acc += __shfl_xor(acc, d, 64);
    if (lane == 0) scores[s] = acc;
}

__global__ __launch_bounds__(1024) void attn_softmax(
    const float* __restrict__ scores, float* __restrict__ wts)
{
    __shared__ float rmax[16];
    __shared__ float rsum[16];
    const int tid = threadIdx.x, lane = tid & 63, wv = tid >> 6;
    const float4 v = ((const float4*)scores)[tid];
    float m = fmaxf(fmaxf(v.x, v.y), fmaxf(v.z, v.w));
#pragma unroll
    for (int d = 32; d > 0; d >>= 1) m = fmaxf(m, __shfl_xor(m, d, 64));
    if (lane == 0) rmax[wv] = m;
    __syncthreads();
    float gm = rmax[0];
#pragma unroll
    for (int i = 1; i < 16; ++i) gm = fmaxf(gm, rmax[i]);
    const float e0 = expf(v.x - gm), e1 = expf(v.y - gm), e2 = expf(v.z - gm), e3 = expf(v.w - gm);
    float s = e0 + e1 + e2 + e3;
#pragma unroll
    for (int d = 32; d > 0; d >>= 1) s += __shfl_xor(s, d, 64);
    if (lane == 0) rsum[wv] = s;
    __syncthreads();
    float gs = 0.f;
#pragma unroll
    for (int i = 0; i < 16; ++i) gs += rsum[i];
    const float inv = 1.0f / gs;
    ((float4*)wts)[tid] = make_float4(e0 * inv, e1 * inv, e2 * inv, e3 * inv);
}

__global__ __launch_bounds__(256) void attn_context(
    const float* __restrict__ wts, const float* __restrict__ enc,
    float* __restrict__ ctx)
{
    __shared__ float red[16][16];
    const int ci = threadIdx.x & 15, ri = threadIdx.x >> 4;
    const int col = blockIdx.x * 16 + ci;
    float acc = 0.f;
    for (int r = ri; r < SDIM; r += 16)
        acc += wts[r] * enc[(size_t)r * HDIM + col];
    red[ri][ci] = acc;
    __syncthreads();
    if (ri == 0) {
        float s = 0.f;
#pragma unroll
        for (int k = 0; k < 16; ++k) s += red[k][ci];
        ctx[col] = s;
    }
}

__global__ __launch_bounds__(256) void attn_final(
    const float* __restrict__ ctx, const float* __restrict__ h2,
    const float* __restrict__ w_cat, const float* __restrict__ b_cat,
    float* __restrict__ out)
{
    const int lane = threadIdx.x & 63, wv = threadIdx.x >> 6;
    const int j = (blockIdx.x << 2) + wv;
    const float4* wc1 = (const float4*)(w_cat + (size_t)j * 2048);
    const float4* wc2 = (const float4*)(w_cat + (size_t)j * 2048 + 1024);
    const float4* c4 = (const float4*)ctx;
    const float4* h4 = (const float4*)h2;
    float acc = 0.f;
#pragma unroll
    for (int k = 0; k < 4; ++k) {
        const int idx = lane + (k << 6);
        float4 a = wc1[idx], b = c4[idx];
        acc += a.x * b.x + a.y * b.y + a.z * b.z + a.w * b.w;
        a = wc2[idx]; b = h4[idx];
        acc += a.x * b.x + a.y * b.y + a.z * b.z + a.w * b.w;
    }
#pragma unroll
    for (int d = 32; d > 0; d >>= 1) acc += __shfl_xor(acc, d, 64);
    if (lane == 0) out[j] = tanhf(acc + b_cat[j]);
}

// ---------------------------------------------------------------------------
extern "C" void kernel_launch(void* const* d_in, const int* in_sizes, int n_in,
                              void* d_out, int out_size, void* d_ws, size_t ws_size,
                              hipStream_t stream)
{
    (void)in_sizes; (void)n_in; (void)out_size; (void)ws_size;
    const float* x     = (const float*)d_in[0];
    const float* enc   = (const float*)d_in[1];
    const float* h0all = (const float*)d_in[2];
    const float* c0all = (const float*)d_in[3];
    const float* w_ih0 = (const float*)d_in[4];
    const float* w_hh0 = (const float*)d_in[5];
    const float* b_ih0 = (const float*)d_in[6];
    const float* b_hh0 = (const float*)d_in[7];
    const float* w_ih1 = (const float*)d_in[8];
    const float* w_hh1 = (const float*)d_in[9];
    const float* b_ih1 = (const float*)d_in[10];
    const float* b_hh1 = (const float*)d_in[11];
    const float* w_cat = (const float*)d_in[12];
    const float* b_cat = (const float*)d_in[13];
    float* out = (float*)d_out;

    float* ws = (float*)d_ws;
    float* xg     = ws;                       // 1024*4096 = 4,194,304 floats
    float* out0   = ws + 4194304;             // 1024*1024 = 1,048,576
    float* scores = ws + 4194304 + 1048576;   // 4096
    float* wts    = scores + 4096;            // 4096
    float* ctx    = wts + 4096;               // 1024
    unsigned long long* tagbuf = (unsigned long long*)(ctx + 1024);  // [2][1024]

    float* out1 = out;                 // [1024][1024]
    float* hN   = out + 1048576;       // h1, h2
    float* cN   = out + 1050624;       // c1, c2
    float* attn = out + 1052672;       // 1024

    hipMemsetAsync(tagbuf, 0, 2048 * sizeof(unsigned long long), stream);

    dim3 gg(64, 16);  // N/64, M/64
    gemm_xg<<<gg, 256, 0, stream>>>(x, w_ih0, b_ih0, b_hh0, xg, 1024, 4096, 1024);
    lstm_scan<<<NBLK, 256, 0, stream>>>(xg, w_hh0, h0all, c0all, out0, hN, cN,
                                        tagbuf, 0u);
    gemm_xg<<<gg, 256, 0, stream>>>(out0, w_ih1, b_ih1, b_hh1, xg, 1024, 4096, 1024);
    lstm_scan<<<NBLK, 256, 0, stream>>>(xg, w_hh1, h0all + 1024, c0all + 1024,
                                        out1, hN + 1024, cN + 1024,
                                        tagbuf, (unsigned)T_STEPS);
    attn_scores<<<1024, 256, 0, stream>>>(enc, hN + 1024, scores);
    attn_softmax<<<1, 1024, 0, stream>>>(scores, wts);
    attn_context<<<64, 256, 0, stream>>>(wts, enc, ctx);
    attn_final<<<256, 256, 0, stream>>>(ctx, hN + 1024, w_cat, b_cat, attn);
}

// Round 5
// 4170.398 us; speedup vs baseline: 1.8701x; 1.8701x over previous
//
#include <hip/hip_runtime.h>
#include <hip/hip_bf16.h>
#include <math.h>

#define T_STEPS 1024
#define HDIM    1024
#define SDIM    4096
#define NBLK    256

// fast transcendentals (v_exp_f32 + v_rcp_f32); |err| ~1e-6, fine vs 2.7e-2 thr
__device__ __forceinline__ float sigmoid_f(float x) {
    return __builtin_amdgcn_rcpf(1.0f + __expf(-x));
}
__device__ __forceinline__ float tanh_f(float x) {
    return 1.0f - 2.0f * __builtin_amdgcn_rcpf(1.0f + __expf(2.0f * x));
}

union H2U { unsigned u; _Float16 h[2]; unsigned short s[2]; };

__device__ __forceinline__ bool slot_ok(unsigned long long v) {
    return (((v      ) & 0xFFFFull) != 0xFFFFull) &&
           (((v >> 16) & 0xFFFFull) != 0xFFFFull) &&
           (((v >> 32) & 0xFFFFull) != 0xFFFFull) &&
           (((v >> 48)           ) != 0xFFFFull);
}

// ---------------------------------------------------------------------------
// Prep: fp32 -> fp16 weight conversion, bias sum
// ---------------------------------------------------------------------------
__global__ __launch_bounds__(256) void cvt_fp16(
    const float* __restrict__ in, _Float16* __restrict__ o, int n)
{
    const int i = (blockIdx.x * 256 + threadIdx.x) * 8;
    if (i + 7 < n) {
        const float4 a = *(const float4*)(in + i);
        const float4 b = *(const float4*)(in + i + 4);
        H2U p0, p1, p2, p3;
        p0.h[0] = (_Float16)a.x; p0.h[1] = (_Float16)a.y;
        p1.h[0] = (_Float16)a.z; p1.h[1] = (_Float16)a.w;
        p2.h[0] = (_Float16)b.x; p2.h[1] = (_Float16)b.y;
        p3.h[0] = (_Float16)b.z; p3.h[1] = (_Float16)b.w;
        *(uint4*)(o + i) = make_uint4(p0.u, p1.u, p2.u, p3.u);
    }
}

__global__ __launch_bounds__(256) void bias_sum(
    const float* __restrict__ a, const float* __restrict__ b, float* __restrict__ o)
{
    const int i = blockIdx.x * 256 + threadIdx.x;
    o[i] = a[i] + b[i];
}

// ---------------------------------------------------------------------------
// GEMM: C[M][N] = X[M][K] @ W[N][K]^T + (b1[N] + b2[N])   (xg0 precompute)
// ---------------------------------------------------------------------------
__global__ __launch_bounds__(256) void gemm_xg(
    const float* __restrict__ X, const float* __restrict__ W,
    const float* __restrict__ b1, const float* __restrict__ b2,
    float* __restrict__ C, int M, int N, int K)
{
    __shared__ float As[16][64];
    __shared__ float Bs[16][64];
    const int tid = threadIdx.x;
    const int m0 = blockIdx.y * 64, n0 = blockIdx.x * 64;
    const int tx = tid & 15, ty = tid >> 4;
    const int lr = tid >> 2, ls = (tid & 3) << 2;
    float acc[4][4] = {};

    for (int kt = 0; kt < K; kt += 16) {
        const float4 xa = *(const float4*)(X + (size_t)(m0 + lr) * K + kt + ls);
        const float4 wb = *(const float4*)(W + (size_t)(n0 + lr) * K + kt + ls);
        __syncthreads();
        As[ls + 0][lr] = xa.x; As[ls + 1][lr] = xa.y; As[ls + 2][lr] = xa.z; As[ls + 3][lr] = xa.w;
        Bs[ls + 0][lr] = wb.x; Bs[ls + 1][lr] = wb.y; Bs[ls + 2][lr] = wb.z; Bs[ls + 3][lr] = wb.w;
        __syncthreads();
#pragma unroll
        for (int k = 0; k < 16; ++k) {
            const float4 a = *(const float4*)&As[k][ty << 2];
            const float4 b = *(const float4*)&Bs[k][tx << 2];
            acc[0][0] += a.x * b.x; acc[0][1] += a.x * b.y; acc[0][2] += a.x * b.z; acc[0][3] += a.x * b.w;
            acc[1][0] += a.y * b.x; acc[1][1] += a.y * b.y; acc[1][2] += a.y * b.z; acc[1][3] += a.y * b.w;
            acc[2][0] += a.z * b.x; acc[2][1] += a.z * b.y; acc[2][2] += a.z * b.z; acc[2][3] += a.z * b.w;
            acc[3][0] += a.w * b.x; acc[3][1] += a.w * b.y; acc[3][2] += a.w * b.z; acc[3][3] += a.w * b.w;
        }
    }
    const int gn = n0 + (tx << 2);
    const float4 bias = make_float4(b1[gn + 0] + b2[gn + 0], b1[gn + 1] + b2[gn + 1],
                                    b1[gn + 2] + b2[gn + 2], b1[gn + 3] + b2[gn + 3]);
#pragma unroll
    for (int i = 0; i < 4; ++i) {
        float4 o = make_float4(acc[i][0] + bias.x, acc[i][1] + bias.y,
                               acc[i][2] + bias.z, acc[i][3] + bias.w);
        *(float4*)(C + (size_t)(m0 + (ty << 2) + i) * N + gn) = o;
    }
}

// ---------------------------------------------------------------------------
// Fused 2-layer persistent LSTM, 1-step pipeline skew.
// blocks 0..127 = layer0 (cols 8b..8b+7), 128..255 = layer1.
// Exchange: per block per step ONE 16B slot (8 cols x fp16) in a T-deep
// one-shot buffer bcX[t][256 u64]; canary 0xFFFF (fp16 NaN, impossible for
// |h|<1); u64 halves self-validating -> single fabric RT, no fences/tags.
// Thread tid polls u64 #tid (cols 4*tid..4*tid+3). Weights fp16, preloaded
// into regs BEFORE the poll (latency hides under the wait).
// Per-thread output-group: o=tid>>3 (col_local=o>>2, gate=o&3), 8 lanes/dot,
// 3-level shfl reduce, shfl-gather of 4 gates per 32-lane half-wave.
// ---------------------------------------------------------------------------
__global__ __launch_bounds__(256, 1) void lstm_fused(
    const float* __restrict__ xg0,        // [T][4H] layer0 gate biases
    const _Float16* __restrict__ wh0h,    // [4H][H] fp16
    const _Float16* __restrict__ wi1h,    // [4H][H] fp16
    const _Float16* __restrict__ wh1h,    // [4H][H] fp16
    const float* __restrict__ b1sum,      // [4H]
    const float* __restrict__ h0all, const float* __restrict__ c0all,
    float* __restrict__ out1,             // [T][H]
    float* __restrict__ hN, float* __restrict__ cN,   // [2][H]
    unsigned long long* bc0, unsigned long long* bc1) // [T][256] each, 0xFF-set
{
    __shared__ float xin[HDIM];
    __shared__ float hin[HDIM];
    __shared__ __align__(16) unsigned short hpack[8];

    const int tid = threadIdx.x;
    const int layer = blockIdx.x >> 7;
    const int blk = blockIdx.x & 127;
    const int gl = tid & 7;           // lane-in-group
    const int col_local = tid >> 5;
    const int gate = (tid >> 3) & 3;
    const int col = blk * 8 + col_local;
    const int row = gate * HDIM + col;

    float cst = c0all[layer * HDIM + col];
    float h_out = 0.0f;

    if (layer == 0) {
        const _Float16* wrow = wh0h + (size_t)row * HDIM;
        for (int t = 0; t < T_STEPS; ++t) {
            float xb[4];
#pragma unroll
            for (int k = 0; k < 4; ++k) xb[k] = xg0[(size_t)t * 4096 + k * 1024 + col];
            uint4 wv[16];
#pragma unroll
            for (int q = 0; q < 16; ++q) wv[q] = ((const uint4*)wrow)[gl + 8 * q];
            __builtin_amdgcn_sched_barrier(0);

            if (t == 0) {
                *(float4*)&hin[4 * tid] = ((const float4*)h0all)[tid];
            } else {
                unsigned long long* p = bc0 + (size_t)(t - 1) * 256 + tid;
                unsigned long long v;
                do { v = __hip_atomic_load(p, __ATOMIC_RELAXED, __HIP_MEMORY_SCOPE_AGENT); }
                while (!slot_ok(v));
                H2U a, b; a.u = (unsigned)v; b.u = (unsigned)(v >> 32);
                *(float4*)&hin[4 * tid] = make_float4((float)a.h[0], (float)a.h[1],
                                                      (float)b.h[0], (float)b.h[1]);
            }
            __syncthreads();

            float acc = 0.f;
#pragma unroll
            for (int q = 0; q < 16; ++q) {
                const int base = 8 * (gl + 8 * q);
                const float4 ha = *(const float4*)&hin[base];
                const float4 hb = *(const float4*)&hin[base + 4];
                H2U p0;
                p0.u = wv[q].x; acc += (float)p0.h[0] * ha.x + (float)p0.h[1] * ha.y;
                p0.u = wv[q].y; acc += (float)p0.h[0] * ha.z + (float)p0.h[1] * ha.w;
                p0.u = wv[q].z; acc += (float)p0.h[0] * hb.x + (float)p0.h[1] * hb.y;
                p0.u = wv[q].w; acc += (float)p0.h[0] * hb.z + (float)p0.h[1] * hb.w;
            }
            acc += __shfl_xor(acc, 1, 64); acc += __shfl_xor(acc, 2, 64); acc += __shfl_xor(acc, 4, 64);
            const int B = tid & 32;
            const float g0 = __shfl(acc, B + 0, 64);
            const float g1 = __shfl(acc, B + 8, 64);
            const float g2 = __shfl(acc, B + 16, 64);
            const float g3 = __shfl(acc, B + 24, 64);
            const float ig = sigmoid_f(g0 + xb[0]);
            const float fg = sigmoid_f(g1 + xb[1]);
            const float gv = tanh_f(g2 + xb[2]);
            const float og = sigmoid_f(g3 + xb[3]);
            cst = fg * cst + ig * gv;
            h_out = og * tanh_f(cst);

            if ((tid & 31) == 0) {
                H2U hv; hv.h[0] = (_Float16)h_out;
                hpack[col_local] = hv.s[0];
                if (t == T_STEPS - 1) { hN[col] = h_out; cN[col] = cst; }
            }
            __syncthreads();
            if (tid == 0) {
                const uint4 pk = *(const uint4*)hpack;
                const unsigned long long lo = (unsigned long long)pk.x | ((unsigned long long)pk.y << 32);
                const unsigned long long hi = (unsigned long long)pk.z | ((unsigned long long)pk.w << 32);
                unsigned long long* dst = bc0 + (size_t)t * 256 + blk * 2;
                __hip_atomic_store(dst,     lo, __ATOMIC_RELAXED, __HIP_MEMORY_SCOPE_AGENT);
                __hip_atomic_store(dst + 1, hi, __ATOMIC_RELAXED, __HIP_MEMORY_SCOPE_AGENT);
            }
        }
    } else {
        const _Float16* wrx = wi1h + (size_t)row * HDIM;
        const _Float16* wrh = wh1h + (size_t)row * HDIM;
        float xb[4];
#pragma unroll
        for (int k = 0; k < 4; ++k) xb[k] = b1sum[k * 1024 + col];

        for (int t = 0; t < T_STEPS; ++t) {
            uint4 wxv[16], whv[16];
#pragma unroll
            for (int q = 0; q < 16; ++q) wxv[q] = ((const uint4*)wrx)[gl + 8 * q];
#pragma unroll
            for (int q = 0; q < 16; ++q) whv[q] = ((const uint4*)wrh)[gl + 8 * q];
            __builtin_amdgcn_sched_barrier(0);

            if (t == 0)
                *(float4*)&hin[4 * tid] = ((const float4*)(h0all + HDIM))[tid];

            unsigned long long* px = bc0 + (size_t)t * 256 + tid;
            unsigned long long* ph = bc1 + (size_t)(t - 1) * 256 + tid;
            unsigned long long vx = 0, vh = 0;
            bool rx = false, rh = (t == 0);
            do {
                if (!rx) { vx = __hip_atomic_load(px, __ATOMIC_RELAXED, __HIP_MEMORY_SCOPE_AGENT); rx = slot_ok(vx); }
                if (!rh) { vh = __hip_atomic_load(ph, __ATOMIC_RELAXED, __HIP_MEMORY_SCOPE_AGENT); rh = slot_ok(vh); }
            } while (!(rx && rh));
            {
                H2U a, b; a.u = (unsigned)vx; b.u = (unsigned)(vx >> 32);
                *(float4*)&xin[4 * tid] = make_float4((float)a.h[0], (float)a.h[1],
                                                      (float)b.h[0], (float)b.h[1]);
                if (t > 0) {
                    H2U c_, d_; c_.u = (unsigned)vh; d_.u = (unsigned)(vh >> 32);
                    *(float4*)&hin[4 * tid] = make_float4((float)c_.h[0], (float)c_.h[1],
                                                          (float)d_.h[0], (float)d_.h[1]);
                }
            }
            __syncthreads();

            float acc = 0.f;
#pragma unroll
            for (int q = 0; q < 16; ++q) {
                const int base = 8 * (gl + 8 * q);
                const float4 xa = *(const float4*)&xin[base];
                const float4 xc = *(const float4*)&xin[base + 4];
                H2U p0;
                p0.u = wxv[q].x; acc += (float)p0.h[0] * xa.x + (float)p0.h[1] * xa.y;
                p0.u = wxv[q].y; acc += (float)p0.h[0] * xa.z + (float)p0.h[1] * xa.w;
                p0.u = wxv[q].z; acc += (float)p0.h[0] * xc.x + (float)p0.h[1] * xc.y;
                p0.u = wxv[q].w; acc += (float)p0.h[0] * xc.z + (float)p0.h[1] * xc.w;
            }
#pragma unroll
            for (int q = 0; q < 16; ++q) {
                const int base = 8 * (gl + 8 * q);
                const float4 ha = *(const float4*)&hin[base];
                const float4 hb = *(const float4*)&hin[base + 4];
                H2U p0;
                p0.u = whv[q].x; acc += (float)p0.h[0] * ha.x + (float)p0.h[1] * ha.y;
                p0.u = whv[q].y; acc += (float)p0.h[0] * ha.z + (float)p0.h[1] * ha.w;
                p0.u = whv[q].z; acc += (float)p0.h[0] * hb.x + (float)p0.h[1] * hb.y;
                p0.u = whv[q].w; acc += (float)p0.h[0] * hb.z + (float)p0.h[1] * hb.w;
            }
            acc += __shfl_xor(acc, 1, 64); acc += __shfl_xor(acc, 2, 64); acc += __shfl_xor(acc, 4, 64);
            const int B = tid & 32;
            const float g0 = __shfl(acc, B + 0, 64);
            const float g1 = __shfl(acc, B + 8, 64);
            const float g2 = __shfl(acc, B + 16, 64);
            const float g3 = __shfl(acc, B + 24, 64);
            const float ig = sigmoid_f(g0 + xb[0]);
            const float fg = sigmoid_f(g1 + xb[1]);
            const float gv = tanh_f(g2 + xb[2]);
            const float og = sigmoid_f(g3 + xb[3]);
            cst = fg * cst + ig * gv;
            h_out = og * tanh_f(cst);

            if ((tid & 31) == 0) {
                H2U hv; hv.h[0] = (_Float16)h_out;
                hpack[col_local] = hv.s[0];
                out1[(size_t)t * HDIM + col] = h_out;
                if (t == T_STEPS - 1) { hN[HDIM + col] = h_out; cN[HDIM + col] = cst; }
            }
            __syncthreads();
            if (tid == 0) {
                const uint4 pk = *(const uint4*)hpack;
                const unsigned long long lo = (unsigned long long)pk.x | ((unsigned long long)pk.y << 32);
                const unsigned long long hi = (unsigned long long)pk.z | ((unsigned long long)pk.w << 32);
                unsigned long long* dst = bc1 + (size_t)t * 256 + blk * 2;
                __hip_atomic_store(dst,     lo, __ATOMIC_RELAXED, __HIP_MEMORY_SCOPE_AGENT);
                __hip_atomic_store(dst + 1, hi, __ATOMIC_RELAXED, __HIP_MEMORY_SCOPE_AGENT);
            }
        }
    }
}

// ---------------------------------------------------------------------------
// v4 fallback scan (used if ws_size too small for the fused path)
// ---------------------------------------------------------------------------
#define PIN4(v) asm volatile("" : "+v"(v.x), "+v"(v.y), "+v"(v.z), "+v"(v.w))

__global__ __launch_bounds__(256, 1) void lstm_scan(
    const float* __restrict__ xg, const float* __restrict__ w_hh,
    const float* __restrict__ h0, const float* __restrict__ c0,
    float* __restrict__ ys, float* __restrict__ hN, float* __restrict__ cN,
    unsigned long long* __restrict__ tagbuf, unsigned tag_base)
{
    __shared__ float h_lds[HDIM];
    const int tid = threadIdx.x, lane = tid & 63, wv = tid >> 6;
    const int j = (blockIdx.x << 2) + wv;

    const float4* r0 = (const float4*)(w_hh + (size_t)j * HDIM);
    const float4* r1 = (const float4*)(w_hh + (size_t)(j + HDIM) * HDIM);
    const float4* r2 = (const float4*)(w_hh + (size_t)(j + 2 * HDIM) * HDIM);
    const float4* r3 = (const float4*)(w_hh + (size_t)(j + 3 * HDIM) * HDIM);
    float4 w0[4], w1[4], w2[4], w3[4];
#pragma unroll
    for (int k = 0; k < 4; ++k) {
        const int idx = lane + (k << 6);
        w0[k] = r0[idx]; w1[k] = r1[idx]; w2[k] = r2[idx]; w3[k] = r3[idx];
    }
#pragma unroll
    for (int k = 0; k < 4; ++k) { PIN4(w0[k]); PIN4(w1[k]); PIN4(w2[k]); PIN4(w3[k]); }

    float c = c0[j];
    float h_out = 0.0f;

    for (int t = 0; t < T_STEPS; ++t) {
        const float* xgt = xg + (size_t)t * (4 * HDIM);
        const float xb_i = xgt[j];
        const float xb_f = xgt[j + HDIM];
        const float xb_g = xgt[j + 2 * HDIM];
        const float xb_o = xgt[j + 3 * HDIM];

        if (t == 0) {
#pragma unroll
            for (int q = 0; q < 4; ++q) h_lds[tid + (q << 8)] = h0[tid + (q << 8)];
        } else {
            const unsigned long long* row = tagbuf + ((size_t)((t - 1) & 1) << 10);
            const unsigned want = tag_base + (unsigned)t;
            unsigned long long v0, v1, v2, v3;
            for (;;) {
                v0 = __hip_atomic_load(row + tid,       __ATOMIC_RELAXED, __HIP_MEMORY_SCOPE_AGENT);
                v1 = __hip_atomic_load(row + tid + 256, __ATOMIC_RELAXED, __HIP_MEMORY_SCOPE_AGENT);
                v2 = __hip_atomic_load(row + tid + 512, __ATOMIC_RELAXED, __HIP_MEMORY_SCOPE_AGENT);
                v3 = __hip_atomic_load(row + tid + 768, __ATOMIC_RELAXED, __HIP_MEMORY_SCOPE_AGENT);
                const bool ok = ((unsigned)(v0 >> 32) == want) & ((unsigned)(v1 >> 32) == want) &
                                ((unsigned)(v2 >> 32) == want) & ((unsigned)(v3 >> 32) == want);
                if (ok) break;
            }
            union { unsigned u; float f; } c0_, c1_, c2_, c3_;
            c0_.u = (unsigned)v0; c1_.u = (unsigned)v1; c2_.u = (unsigned)v2; c3_.u = (unsigned)v3;
            h_lds[tid] = c0_.f; h_lds[tid + 256] = c1_.f;
            h_lds[tid + 512] = c2_.f; h_lds[tid + 768] = c3_.f;
        }
        __syncthreads();

        float gi = 0.f, gf = 0.f, gg = 0.f, go = 0.f;
#pragma unroll
        for (int k = 0; k < 4; ++k) {
            const float4 hv = *(const float4*)&h_lds[4 * (lane + (k << 6))];
            gi += w0[k].x * hv.x + w0[k].y * hv.y + w0[k].z * hv.z + w0[k].w * hv.w;
            gf += w1[k].x * hv.x + w1[k].y * hv.y + w1[k].z * hv.z + w1[k].w * hv.w;
            gg += w2[k].x * hv.x + w2[k].y * hv.y + w2[k].z * hv.z + w2[k].w * hv.w;
            go += w3[k].x * hv.x + w3[k].y * hv.y + w3[k].z * hv.z + w3[k].w * hv.w;
        }
#pragma unroll
        for (int d = 32; d > 0; d >>= 1) {
            gi += __shfl_xor(gi, d, 64);
            gf += __shfl_xor(gf, d, 64);
            gg += __shfl_xor(gg, d, 64);
            go += __shfl_xor(go, d, 64);
        }
        const float ig = sigmoid_f(gi + xb_i), fg = sigmoid_f(gf + xb_f), og = sigmoid_f(go + xb_o);
        const float gv = tanh_f(gg + xb_g);
        c = fg * c + ig * gv;
        h_out = og * tanh_f(c);

        if (lane == 0) {
            ys[(size_t)t * HDIM + j] = h_out;
            union { float f; unsigned u; } hu; hu.f = h_out;
            const unsigned long long pk =
                ((unsigned long long)(tag_base + (unsigned)t + 1u) << 32) | (unsigned long long)hu.u;
            __hip_atomic_store(tagbuf + ((size_t)(t & 1) << 10) + j, pk,
                               __ATOMIC_RELAXED, __HIP_MEMORY_SCOPE_AGENT);
        }
    }
    if (lane == 0) { hN[j] = h_out; cN[j] = c; }
}

// ---------------------------------------------------------------------------
// Attention
// ---------------------------------------------------------------------------
__global__ __launch_bounds__(256) void attn_scores(
    const float* __restrict__ enc, const float* __restrict__ tgt,
    float* __restrict__ scores)
{
    const int lane = threadIdx.x & 63, wv = threadIdx.x >> 6;
    const int s = (blockIdx.x << 2) + wv;
    const float4* e4 = (const float4*)(enc + (size_t)s * HDIM);
    const float4* t4 = (const float4*)tgt;
    float acc = 0.f;
#pragma unroll
    for (int k = 0; k < 4; ++k) {
        const int idx = lane + (k << 6);
        const float4 e = e4[idx], t = t4[idx];
        acc += e.x * t.x + e.y * t.y + e.z * t.z + e.w * t.w;
    }
#pragma unroll
    for (int d = 32; d > 0; d >>= 1) acc += __shfl_xor(acc, d, 64);
    if (lane == 0) scores[s] = acc;
}

__global__ __launch_bounds__(1024) void attn_softmax(
    const float* __restrict__ scores, float* __restrict__ wts)
{
    __shared__ float rmax[16];
    __shared__ float rsum[16];
    const int tid = threadIdx.x, lane = tid & 63, wv = tid >> 6;
    const float4 v = ((const float4*)scores)[tid];
    float m = fmaxf(fmaxf(v.x, v.y), fmaxf(v.z, v.w));
#pragma unroll
    for (int d = 32; d > 0; d >>= 1) m = fmaxf(m, __shfl_xor(m, d, 64));
    if (lane == 0) rmax[wv] = m;
    __syncthreads();
    float gm = rmax[0];
#pragma unroll
    for (int i = 1; i < 16; ++i) gm = fmaxf(gm, rmax[i]);
    const float e0 = expf(v.x - gm), e1 = expf(v.y - gm), e2 = expf(v.z - gm), e3 = expf(v.w - gm);
    float s = e0 + e1 + e2 + e3;
#pragma unroll
    for (int d = 32; d > 0; d >>= 1) s += __shfl_xor(s, d, 64);
    if (lane == 0) rsum[wv] = s;
    __syncthreads();
    float gs = 0.f;
#pragma unroll
    for (int i = 0; i < 16; ++i) gs += rsum[i];
    const float inv = 1.0f / gs;
    ((float4*)wts)[tid] = make_float4(e0 * inv, e1 * inv, e2 * inv, e3 * inv);
}

__global__ __launch_bounds__(256) void attn_context(
    const float* __restrict__ wts, const float* __restrict__ enc,
    float* __restrict__ ctx)
{
    __shared__ float red[16][16];
    const int ci = threadIdx.x & 15, ri = threadIdx.x >> 4;
    const int col = blockIdx.x * 16 + ci;
    float acc = 0.f;
    for (int r = ri; r < SDIM; r += 16)
        acc += wts[r] * enc[(size_t)r * HDIM + col];
    red[ri][ci] = acc;
    __syncthreads();
    if (ri == 0) {
        float s = 0.f;
#pragma unroll
        for (int k = 0; k < 16; ++k) s += red[k][ci];
        ctx[col] = s;
    }
}

__global__ __launch_bounds__(256) void attn_final(
    const float* __restrict__ ctx, const float* __restrict__ h2,
    const float* __restrict__ w_cat, const float* __restrict__ b_cat,
    float* __restrict__ out)
{
    const int lane = threadIdx.x & 63, wv = threadIdx.x >> 6;
    const int j = (blockIdx.x << 2) + wv;
    const float4* wc1 = (const float4*)(w_cat + (size_t)j * 2048);
    const float4* wc2 = (const float4*)(w_cat + (size_t)j * 2048 + 1024);
    const float4* c4 = (const float4*)ctx;
    const float4* h4 = (const float4*)h2;
    float acc = 0.f;
#pragma unroll
    for (int k = 0; k < 4; ++k) {
        const int idx = lane + (k << 6);
        float4 a = wc1[idx], b = c4[idx];
        acc += a.x * b.x + a.y * b.y + a.z * b.z + a.w * b.w;
        a = wc2[idx]; b = h4[idx];
        acc += a.x * b.x + a.y * b.y + a.z * b.z + a.w * b.w;
    }
#pragma unroll
    for (int d = 32; d > 0; d >>= 1) acc += __shfl_xor(acc, d, 64);
    if (lane == 0) out[j] = tanhf(acc + b_cat[j]);
}

// ---------------------------------------------------------------------------
extern "C" void kernel_launch(void* const* d_in, const int* in_sizes, int n_in,
                              void* d_out, int out_size, void* d_ws, size_t ws_size,
                              hipStream_t stream)
{
    (void)in_sizes; (void)n_in; (void)out_size;
    const float* x     = (const float*)d_in[0];
    const float* enc   = (const float*)d_in[1];
    const float* h0all = (const float*)d_in[2];
    const float* c0all = (const float*)d_in[3];
    const float* w_ih0 = (const float*)d_in[4];
    const float* w_hh0 = (const float*)d_in[5];
    const float* b_ih0 = (const float*)d_in[6];
    const float* b_hh0 = (const float*)d_in[7];
    const float* w_ih1 = (const float*)d_in[8];
    const float* w_hh1 = (const float*)d_in[9];
    const float* b_ih1 = (const float*)d_in[10];
    const float* b_hh1 = (const float*)d_in[11];
    const float* w_cat = (const float*)d_in[12];
    const float* b_cat = (const float*)d_in[13];
    float* out = (float*)d_out;

    float* out1 = out;                 // [1024][1024]
    float* hN   = out + 1048576;       // h1, h2
    float* cN   = out + 1050624;       // c1, c2
    float* attn = out + 1052672;       // 1024

    float* ws = (float*)d_ws;

    const size_t FUSED_WS_BYTES = 46200000;  // ~46.2 MB layout below
    if (ws_size >= FUSED_WS_BYTES) {
        // fused-path layout (float offsets)
        float* xg0        = ws;                       // 4,194,304
        _Float16* wh0h    = (_Float16*)(ws + 4194304);   // 4M fp16 (2,097,152 slots)
        _Float16* wi1h    = (_Float16*)(ws + 6291456);
        _Float16* wh1h    = (_Float16*)(ws + 8388608);
        float* b1s        = ws + 10485760;            // 4096
        unsigned long long* bc0 = (unsigned long long*)(ws + 10489856); // 262144 u64
        unsigned long long* bc1 = (unsigned long long*)(ws + 11014144);
        float* scores     = ws + 11538432;            // 4096
        float* wts        = scores + 4096;
        float* ctx        = wts + 4096;

        hipMemsetAsync(bc0, 0xFF, 2 * 262144 * sizeof(unsigned long long), stream);
        cvt_fp16<<<2048, 256, 0, stream>>>(w_hh0, wh0h, 4194304);
        cvt_fp16<<<2048, 256, 0, stream>>>(w_ih1, wi1h, 4194304);
        cvt_fp16<<<2048, 256, 0, stream>>>(w_hh1, wh1h, 4194304);
        bias_sum<<<16, 256, 0, stream>>>(b_ih1, b_hh1, b1s);

        dim3 gg(64, 16);
        gemm_xg<<<gg, 256, 0, stream>>>(x, w_ih0, b_ih0, b_hh0, xg0, 1024, 4096, 1024);
        lstm_fused<<<256, 256, 0, stream>>>(xg0, wh0h, wi1h, wh1h, b1s,
                                            h0all, c0all, out1, hN, cN, bc0, bc1);
        attn_scores<<<1024, 256, 0, stream>>>(enc, hN + 1024, scores);
        attn_softmax<<<1, 1024, 0, stream>>>(scores, wts);
        attn_context<<<64, 256, 0, stream>>>(wts, enc, ctx);
        attn_final<<<256, 256, 0, stream>>>(ctx, hN + 1024, w_cat, b_cat, attn);
    } else {
        // v4 fallback
        float* xg     = ws;
        float* out0   = ws + 4194304;
        float* scores = ws + 4194304 + 1048576;
        float* wts    = scores + 4096;
        float* ctx    = wts + 4096;
        unsigned long long* tagbuf = (unsigned long long*)(ctx + 1024);

        hipMemsetAsync(tagbuf, 0, 2048 * sizeof(unsigned long long), stream);
        dim3 gg(64, 16);
        gemm_xg<<<gg, 256, 0, stream>>>(x, w_ih0, b_ih0, b_hh0, xg, 1024, 4096, 1024);
        lstm_scan<<<NBLK, 256, 0, stream>>>(xg, w_hh0, h0all, c0all, out0, hN, cN, tagbuf, 0u);
        gemm_xg<<<gg, 256, 0, stream>>>(out0, w_ih1, b_ih1, b_hh1, xg, 1024, 4096, 1024);
        lstm_scan<<<NBLK, 256, 0, stream>>>(xg, w_hh1, h0all + 1024, c0all + 1024,
                                            out1, hN + 1024, cN + 1024, tagbuf + 1024,
                                            (unsigned)T_STEPS);
        attn_scores<<<1024, 256, 0, stream>>>(enc, hN + 1024, scores);
        attn_softmax<<<1, 1024, 0, stream>>>(scores, wts);
        attn_context<<<64, 256, 0, stream>>>(wts, enc, ctx);
        attn_final<<<256, 256, 0, stream>>>(ctx, hN + 1024, w_cat, b_cat, attn);
    }
}

// Round 6
// 3469.577 us; speedup vs baseline: 2.2479x; 1.2020x over previous
//
#include <hip/hip_runtime.h>
#include <hip/hip_bf16.h>
#include <math.h>

#define T_STEPS 1024
#define HDIM    1024
#define SDIM    4096

// fast transcendentals (v_exp_f32 + v_rcp_f32); |err| ~1e-6, fine vs 2.7e-2 thr
__device__ __forceinline__ float sigmoid_f(float x) {
    return __builtin_amdgcn_rcpf(1.0f + __expf(-x));
}
__device__ __forceinline__ float tanh_f(float x) {
    return 1.0f - 2.0f * __builtin_amdgcn_rcpf(1.0f + __expf(2.0f * x));
}

union H2U { unsigned u; _Float16 h[2]; unsigned short s[2]; };

typedef _Float16 half2v __attribute__((ext_vector_type(2)));

// fdot2: fp16 pair dot with fp32 accumulator (v_dot2_f32_f16)
__device__ __forceinline__ float fdot2_(unsigned w, unsigned h, float acc) {
#if __has_builtin(__builtin_amdgcn_fdot2)
    return __builtin_amdgcn_fdot2(__builtin_bit_cast(half2v, w),
                                  __builtin_bit_cast(half2v, h), acc, false);
#else
    const half2v a = __builtin_bit_cast(half2v, w);
    const half2v b = __builtin_bit_cast(half2v, h);
    return acc + (float)a[0] * (float)b[0] + (float)a[1] * (float)b[1];
#endif
}

// opaque 16B load: asm-defined => cannot be rematerialized; forces true
// register residency of preloaded weights across the scan loop.
#define GLOAD16(dst, p) asm volatile("global_load_dwordx4 %0, %1, off" \
                                     : "=v"(dst) : "v"(p))
#define GWAIT() asm volatile("s_waitcnt vmcnt(0)" ::: "memory")

__device__ __forceinline__ unsigned long long lda64(const unsigned long long* p) {
    return __hip_atomic_load(p, __ATOMIC_RELAXED, __HIP_MEMORY_SCOPE_AGENT);
}

// 2-deep rolling poll of two u64 slots (4 columns). Issues the next pair
// BEFORE checking the current one -> compiler emits s_waitcnt vmcnt(2) and the
// poll pipeline runs at ~RT/2 period instead of RT. Valid iff every 16-bit
// canary (hi16 of each u32) is 0x0000; buffer is 0xFF-initialized.
__device__ __forceinline__ void poll2(const unsigned long long* p0,
                                      const unsigned long long* p1,
                                      unsigned long long& r0, unsigned long long& r1) {
    unsigned long long c0 = lda64(p0), c1 = lda64(p1);
    for (;;) {
        const unsigned long long n0 = lda64(p0);
        const unsigned long long n1 = lda64(p1);
        const unsigned t = (unsigned)c0 | (unsigned)(c0 >> 32) |
                           (unsigned)c1 | (unsigned)(c1 >> 32);
        if (t < 0xFFFF0000u) break;   // hi16 of OR != 0xFFFF -> all 4 valid
        c0 = n0; c1 = n1;
    }
    r0 = c0; r1 = c1;
}

__device__ __forceinline__ unsigned pack_pair(unsigned long long v) {
    // {col2i in lo16, col2i+1 in hi16} — matches fp16 weight memory order
    return (unsigned)(v & 0xFFFFu) | (((unsigned)(v >> 32) & 0xFFFFu) << 16);
}

// ---------------------------------------------------------------------------
// Prep kernels
// ---------------------------------------------------------------------------
__global__ __launch_bounds__(256) void cvt_fp16(
    const float* __restrict__ in, _Float16* __restrict__ o, int n)
{
    const int i = (blockIdx.x * 256 + threadIdx.x) * 8;
    if (i + 7 < n) {
        const float4 a = *(const float4*)(in + i);
        const float4 b = *(const float4*)(in + i + 4);
        H2U p0, p1, p2, p3;
        p0.h[0] = (_Float16)a.x; p0.h[1] = (_Float16)a.y;
        p1.h[0] = (_Float16)a.z; p1.h[1] = (_Float16)a.w;
        p2.h[0] = (_Float16)b.x; p2.h[1] = (_Float16)b.y;
        p3.h[0] = (_Float16)b.z; p3.h[1] = (_Float16)b.w;
        *(uint4*)(o + i) = make_uint4(p0.u, p1.u, p2.u, p3.u);
    }
}

__global__ __launch_bounds__(256) void bias_sum(
    const float* __restrict__ a, const float* __restrict__ b, float* __restrict__ o)
{
    const int i = blockIdx.x * 256 + threadIdx.x;
    o[i] = a[i] + b[i];
}

// ---------------------------------------------------------------------------
// GEMM: C[M][N] = X[M][K] @ W[N][K]^T + (b1+b2), fp32 compute, fp16 output
// ---------------------------------------------------------------------------
__global__ __launch_bounds__(256) void gemm_xg_h(
    const float* __restrict__ X, const float* __restrict__ W,
    const float* __restrict__ b1, const float* __restrict__ b2,
    _Float16* __restrict__ C, int M, int N, int K)
{
    __shared__ float As[16][64];
    __shared__ float Bs[16][64];
    const int tid = threadIdx.x;
    const int m0 = blockIdx.y * 64, n0 = blockIdx.x * 64;
    const int tx = tid & 15, ty = tid >> 4;
    const int lr = tid >> 2, ls = (tid & 3) << 2;
    float acc[4][4] = {};

    for (int kt = 0; kt < K; kt += 16) {
        const float4 xa = *(const float4*)(X + (size_t)(m0 + lr) * K + kt + ls);
        const float4 wb = *(const float4*)(W + (size_t)(n0 + lr) * K + kt + ls);
        __syncthreads();
        As[ls + 0][lr] = xa.x; As[ls + 1][lr] = xa.y; As[ls + 2][lr] = xa.z; As[ls + 3][lr] = xa.w;
        Bs[ls + 0][lr] = wb.x; Bs[ls + 1][lr] = wb.y; Bs[ls + 2][lr] = wb.z; Bs[ls + 3][lr] = wb.w;
        __syncthreads();
#pragma unroll
        for (int k = 0; k < 16; ++k) {
            const float4 a = *(const float4*)&As[k][ty << 2];
            const float4 b = *(const float4*)&Bs[k][tx << 2];
            acc[0][0] += a.x * b.x; acc[0][1] += a.x * b.y; acc[0][2] += a.x * b.z; acc[0][3] += a.x * b.w;
            acc[1][0] += a.y * b.x; acc[1][1] += a.y * b.y; acc[1][2] += a.y * b.z; acc[1][3] += a.y * b.w;
            acc[2][0] += a.z * b.x; acc[2][1] += a.z * b.y; acc[2][2] += a.z * b.z; acc[2][3] += a.z * b.w;
            acc[3][0] += a.w * b.x; acc[3][1] += a.w * b.y; acc[3][2] += a.w * b.z; acc[3][3] += a.w * b.w;
        }
    }
    const int gn = n0 + (tx << 2);
    const float4 bias = make_float4(b1[gn + 0] + b2[gn + 0], b1[gn + 1] + b2[gn + 1],
                                    b1[gn + 2] + b2[gn + 2], b1[gn + 3] + b2[gn + 3]);
#pragma unroll
    for (int i = 0; i < 4; ++i) {
        H2U q0, q1;
        q0.h[0] = (_Float16)(acc[i][0] + bias.x);
        q0.h[1] = (_Float16)(acc[i][1] + bias.y);
        q1.h[0] = (_Float16)(acc[i][2] + bias.z);
        q1.h[1] = (_Float16)(acc[i][3] + bias.w);
        *(uint2*)(C + (size_t)(m0 + (ty << 2) + i) * N + gn) = make_uint2(q0.u, q1.u);
    }
}

// ---------------------------------------------------------------------------
// Fused 2-layer persistent LSTM v2.
//  - blocks 0..127: layer0 (cols 8b..8b+7); 128..255: layer1; 1-beat skew.
//  - Exchange: 4B per column {0x0000|fp16} one-shot slots bcX[t][1024] u32,
//    0xFF-init. Column leaders store directly (no funnel, no 2nd barrier).
//  - Weights fully register-resident via opaque asm loads (remat-proof):
//    L0: 64 u32 (wh window), L1: 128 u32 (wx+wh windows).
//  - Dot: fdot2 on fp16-packed h in LDS (8-fold broadcast reads).
//  - amdgpu_waves_per_eu(1,1): 512-VGPR budget + HW-enforced 1 block/CU.
//  - Thread map: wave=tid>>6, lane=tid&63, window w=lane&7 (128 dims),
//    output o=(wave<<3)|(lane>>3); col_local=o>>2, gate=o&3.
//    Reduce: shfl_xor 1,2,4 over the 8 windows; gather 4 gates per half-wave.
//  - Ordering: poll success of step t implies every wave published step t,
//    hence finished reading hbuf[t-1] -> L0 needs only the fill barrier.
//    L1 needs an end-of-step barrier (xbuf overwrite races x-dot otherwise).
// ---------------------------------------------------------------------------
__global__ __launch_bounds__(256)
__attribute__((amdgpu_waves_per_eu(1, 1)))
void lstm_fused2(
    const _Float16* __restrict__ xg0h,    // [T][4H] fp16, bias included
    const _Float16* __restrict__ wh0h,    // [4H][H] fp16
    const _Float16* __restrict__ wi1h,    // [4H][H] fp16
    const _Float16* __restrict__ wh1h,    // [4H][H] fp16
    const float* __restrict__ b1s,        // [4H]
    const float* __restrict__ h0all, const float* __restrict__ c0all,
    float* __restrict__ out1,             // [T][H]
    float* __restrict__ hN, float* __restrict__ cN,   // [2][H]
    unsigned* bc0, unsigned* bc1)         // [T][1024] u32 each, 0xFF-set
{
    __shared__ unsigned hbuf2[512];   // h[t] as packed fp16 pairs
    __shared__ unsigned xbuf2[512];   // layer1: x[t] packed

    const int tid  = threadIdx.x;
    const int wave = tid >> 6, lane = tid & 63;
    const int w    = lane & 7;                    // window (128 dims)
    const int o    = (wave << 3) | (lane >> 3);   // output 0..31
    const int col_local = o >> 2, gate = o & 3;
    const int layer = blockIdx.x >> 7;
    const int blk   = blockIdx.x & 127;
    const int col   = blk * 8 + col_local;
    const int r     = gate * HDIM + col;          // weight row
    const int B     = lane & 32;                  // half-wave base for gathers

    float cst = c0all[layer * HDIM + col];
    float h_out = 0.0f;

    if (layer == 0) {
        // ---- preload recurrent weights into registers (opaque, remat-proof)
        const unsigned* wb = (const unsigned*)wh0h + (size_t)r * 512 + w * 64;
        uint4 wh[16];
#pragma unroll
        for (int i = 0; i < 16; ++i) GLOAD16(wh[i], (const void*)(wb + i * 4));
        GWAIT();

        for (int t = 0; t < T_STEPS; ++t) {
            // gate biases: issued before the wait, latency hidden
            const _Float16* xr = xg0h + (size_t)t * 4096 + col;
            const float xb0 = (float)xr[0],    xb1 = (float)xr[1024];
            const float xb2 = (float)xr[2048], xb3 = (float)xr[3072];

            if (t == 0) {
                H2U a, b;
                a.h[0] = (_Float16)h0all[2 * tid];
                a.h[1] = (_Float16)h0all[2 * tid + 1];
                b.h[0] = (_Float16)h0all[512 + 2 * tid];
                b.h[1] = (_Float16)h0all[512 + 2 * tid + 1];
                hbuf2[tid] = a.u; hbuf2[tid + 256] = b.u;
            } else {
                const unsigned long long* row = (const unsigned long long*)(bc0 + (size_t)(t - 1) * 1024);
                unsigned long long v0, v1;
                poll2(row + tid, row + tid + 256, v0, v1);
                hbuf2[tid] = pack_pair(v0); hbuf2[tid + 256] = pack_pair(v1);
            }
            __syncthreads();

            float acc = 0.f;
#pragma unroll
            for (int q = 0; q < 16; ++q) {
                const uint4 hv = *(const uint4*)&hbuf2[w * 64 + q * 4];
                acc = fdot2_(wh[q].x, hv.x, acc);
                acc = fdot2_(wh[q].y, hv.y, acc);
                acc = fdot2_(wh[q].z, hv.z, acc);
                acc = fdot2_(wh[q].w, hv.w, acc);
            }
            acc += __shfl_xor(acc, 1, 64);
            acc += __shfl_xor(acc, 2, 64);
            acc += __shfl_xor(acc, 4, 64);
            const float g0 = __shfl(acc, B + 0, 64);
            const float g1 = __shfl(acc, B + 8, 64);
            const float g2 = __shfl(acc, B + 16, 64);
            const float g3 = __shfl(acc, B + 24, 64);

            const float ig = sigmoid_f(g0 + xb0);
            const float fg = sigmoid_f(g1 + xb1);
            const float gv = tanh_f(g2 + xb2);
            const float oo = sigmoid_f(g3 + xb3);
            cst = fg * cst + ig * gv;
            h_out = oo * tanh_f(cst);

            if ((lane & 31) == 0) {
                H2U hv; hv.h[0] = (_Float16)h_out;
                __hip_atomic_store(bc0 + (size_t)t * 1024 + col, (unsigned)hv.s[0],
                                   __ATOMIC_RELAXED, __HIP_MEMORY_SCOPE_AGENT);
            }
        }
        if ((lane & 31) == 0) { hN[col] = h_out; cN[col] = cst; }
    } else {
        // ---- preload BOTH weight sets into registers
        const unsigned* wxb = (const unsigned*)wi1h + (size_t)r * 512 + w * 64;
        const unsigned* whb = (const unsigned*)wh1h + (size_t)r * 512 + w * 64;
        uint4 wx[16], wh[16];
#pragma unroll
        for (int i = 0; i < 16; ++i) GLOAD16(wx[i], (const void*)(wxb + i * 4));
#pragma unroll
        for (int i = 0; i < 16; ++i) GLOAD16(wh[i], (const void*)(whb + i * 4));
        GWAIT();

        const float* br = b1s + col;
        const float xb0 = br[0],    xb1 = br[1024];
        const float xb2 = br[2048], xb3 = br[3072];

        for (int t = 0; t < T_STEPS; ++t) {
            if (t == 0) {
                H2U a, b;
                a.h[0] = (_Float16)h0all[HDIM + 2 * tid];
                a.h[1] = (_Float16)h0all[HDIM + 2 * tid + 1];
                b.h[0] = (_Float16)h0all[HDIM + 512 + 2 * tid];
                b.h[1] = (_Float16)h0all[HDIM + 512 + 2 * tid + 1];
                hbuf2[tid] = a.u; hbuf2[tid + 256] = b.u;
            }
            // x[t] was published ~1 beat ago: usually a first-poll hit
            {
                const unsigned long long* row = (const unsigned long long*)(bc0 + (size_t)t * 1024);
                unsigned long long v0, v1;
                poll2(row + tid, row + tid + 256, v0, v1);
                xbuf2[tid] = pack_pair(v0); xbuf2[tid + 256] = pack_pair(v1);
            }
            __syncthreads();

            // x-dot runs while the h slots (critical input) are still arriving
            float acc = 0.f;
#pragma unroll
            for (int q = 0; q < 16; ++q) {
                const uint4 xv = *(const uint4*)&xbuf2[w * 64 + q * 4];
                acc = fdot2_(wx[q].x, xv.x, acc);
                acc = fdot2_(wx[q].y, xv.y, acc);
                acc = fdot2_(wx[q].z, xv.z, acc);
                acc = fdot2_(wx[q].w, xv.w, acc);
            }

            if (t > 0) {
                const unsigned long long* row = (const unsigned long long*)(bc1 + (size_t)(t - 1) * 1024);
                unsigned long long v0, v1;
                poll2(row + tid, row + tid + 256, v0, v1);
                hbuf2[tid] = pack_pair(v0); hbuf2[tid + 256] = pack_pair(v1);
            }
            __syncthreads();

#pragma unroll
            for (int q = 0; q < 16; ++q) {
                const uint4 hv = *(const uint4*)&hbuf2[w * 64 + q * 4];
                acc = fdot2_(wh[q].x, hv.x, acc);
                acc = fdot2_(wh[q].y, hv.y, acc);
                acc = fdot2_(wh[q].z, hv.z, acc);
                acc = fdot2_(wh[q].w, hv.w, acc);
            }
            acc += __shfl_xor(acc, 1, 64);
            acc += __shfl_xor(acc, 2, 64);
            acc += __shfl_xor(acc, 4, 64);
            const float g0 = __shfl(acc, B + 0, 64);
            const float g1 = __shfl(acc, B + 8, 64);
            const float g2 = __shfl(acc, B + 16, 64);
            const float g3 = __shfl(acc, B + 24, 64);

            const float ig = sigmoid_f(g0 + xb0);
            const float fg = sigmoid_f(g1 + xb1);
            const float gv = tanh_f(g2 + xb2);
            const float oo = sigmoid_f(g3 + xb3);
            cst = fg * cst + ig * gv;
            h_out = oo * tanh_f(cst);

            if ((lane & 31) == 0) {
                out1[(size_t)t * HDIM + col] = h_out;
                H2U hv; hv.h[0] = (_Float16)h_out;
                __hip_atomic_store(bc1 + (size_t)t * 1024 + col, (unsigned)hv.s[0],
                                   __ATOMIC_RELAXED, __HIP_MEMORY_SCOPE_AGENT);
            }
            __syncthreads();   // xbuf overwrite at t+1 must wait for all waves
        }
        if ((lane & 31) == 0) { hN[HDIM + col] = h_out; cN[HDIM + col] = cst; }
    }
}

// ---------------------------------------------------------------------------
// Attention
// ---------------------------------------------------------------------------
__global__ __launch_bounds__(256) void attn_scores(
    const float* __restrict__ enc, const float* __restrict__ tgt,
    float* __restrict__ scores)
{
    const int lane = threadIdx.x & 63, wv = threadIdx.x >> 6;
    const int s = (blockIdx.x << 2) + wv;
    const float4* e4 = (const float4*)(enc + (size_t)s * HDIM);
    const float4* t4 = (const float4*)tgt;
    float acc = 0.f;
#pragma unroll
    for (int k = 0; k < 4; ++k) {
        const int idx = lane + (k << 6);
        const float4 e = e4[idx], t = t4[idx];
        acc += e.x * t.x + e.y * t.y + e.z * t.z + e.w * t.w;
    }
#pragma unroll
    for (int d = 32; d > 0; d >>= 1) acc += __shfl_xor(acc, d, 64);
    if (lane == 0) scores[s] = acc;
}

__global__ __launch_bounds__(1024) void attn_softmax(
    const float* __restrict__ scores, float* __restrict__ wts)
{
    __shared__ float rmax[16];
    __shared__ float rsum[16];
    const int tid = threadIdx.x, lane = tid & 63, wv = tid >> 6;
    const float4 v = ((const float4*)scores)[tid];
    float m = fmaxf(fmaxf(v.x, v.y), fmaxf(v.z, v.w));
#pragma unroll
    for (int d = 32; d > 0; d >>= 1) m = fmaxf(m, __shfl_xor(m, d, 64));
    if (lane == 0) rmax[wv] = m;
    __syncthreads();
    float gm = rmax[0];
#pragma unroll
    for (int i = 1; i < 16; ++i) gm = fmaxf(gm, rmax[i]);
    const float e0 = expf(v.x - gm), e1 = expf(v.y - gm), e2 = expf(v.z - gm), e3 = expf(v.w - gm);
    float s = e0 + e1 + e2 + e3;
#pragma unroll
    for (int d = 32; d > 0; d >>= 1) s += __shfl_xor(s, d, 64);
    if (lane == 0) rsum[wv] = s;
    __syncthreads();
    float gs = 0.f;
#pragma unroll
    for (int i = 0; i < 16; ++i) gs += rsum[i];
    const float inv = 1.0f / gs;
    ((float4*)wts)[tid] = make_float4(e0 * inv, e1 * inv, e2 * inv, e3 * inv);
}

__global__ __launch_bounds__(256) void attn_context(
    const float* __restrict__ wts, const float* __restrict__ enc,
    float* __restrict__ ctx)
{
    __shared__ float red[16][16];
    const int ci = threadIdx.x & 15, ri = threadIdx.x >> 4;
    const int col = blockIdx.x * 16 + ci;
    float acc = 0.f;
    for (int r = ri; r < SDIM; r += 16)
        acc += wts[r] * enc[(size_t)r * HDIM + col];
    red[ri][ci] = acc;
    __syncthreads();
    if (ri == 0) {
        float s = 0.f;
#pragma unroll
        for (int k = 0; k < 16; ++k) s += red[k][ci];
        ctx[col] = s;
    }
}

__global__ __launch_bounds__(256) void attn_final(
    const float* __restrict__ ctx, const float* __restrict__ h2,
    const float* __restrict__ w_cat, const float* __restrict__ b_cat,
    float* __restrict__ out)
{
    const int lane = threadIdx.x & 63, wv = threadIdx.x >> 6;
    const int j = (blockIdx.x << 2) + wv;
    const float4* wc1 = (const float4*)(w_cat + (size_t)j * 2048);
    const float4* wc2 = (const float4*)(w_cat + (size_t)j * 2048 + 1024);
    const float4* c4 = (const float4*)ctx;
    const float4* h4 = (const float4*)h2;
    float acc = 0.f;
#pragma unroll
    for (int k = 0; k < 4; ++k) {
        const int idx = lane + (k << 6);
        float4 a = wc1[idx], b = c4[idx];
        acc += a.x * b.x + a.y * b.y + a.z * b.z + a.w * b.w;
        a = wc2[idx]; b = h4[idx];
        acc += a.x * b.x + a.y * b.y + a.z * b.z + a.w * b.w;
    }
#pragma unroll
    for (int d = 32; d > 0; d >>= 1) acc += __shfl_xor(acc, d, 64);
    if (lane == 0) out[j] = tanhf(acc + b_cat[j]);
}

// ---------------------------------------------------------------------------
extern "C" void kernel_launch(void* const* d_in, const int* in_sizes, int n_in,
                              void* d_out, int out_size, void* d_ws, size_t ws_size,
                              hipStream_t stream)
{
    (void)in_sizes; (void)n_in; (void)out_size; (void)ws_size;
    const float* x     = (const float*)d_in[0];
    const float* enc   = (const float*)d_in[1];
    const float* h0all = (const float*)d_in[2];
    const float* c0all = (const float*)d_in[3];
    const float* w_ih0 = (const float*)d_in[4];
    const float* w_hh0 = (const float*)d_in[5];
    const float* b_ih0 = (const float*)d_in[6];
    const float* b_hh0 = (const float*)d_in[7];
    const float* w_ih1 = (const float*)d_in[8];
    const float* w_hh1 = (const float*)d_in[9];
    const float* b_ih1 = (const float*)d_in[10];
    const float* b_hh1 = (const float*)d_in[11];
    const float* w_cat = (const float*)d_in[12];
    const float* b_cat = (const float*)d_in[13];
    float* out = (float*)d_out;

    float* out1 = out;                 // [1024][1024]
    float* hN   = out + 1048576;       // h1, h2
    float* cN   = out + 1050624;       // c1, c2
    float* attn = out + 1052672;       // 1024

    // ws layout (bytes); total ~40.1 MB (round-5 proved ws_size >= 46.2 MB)
    char* wsb = (char*)d_ws;
    _Float16* xg0h = (_Float16*)(wsb);                    //  8 MB
    _Float16* wh0h = (_Float16*)(wsb + 8388608);          //  8 MB
    _Float16* wi1h = (_Float16*)(wsb + 16777216);         //  8 MB
    _Float16* wh1h = (_Float16*)(wsb + 25165824);         //  8 MB
    float*    b1s  = (float*)   (wsb + 33554432);         // 16 KB
    unsigned* bc0  = (unsigned*)(wsb + 33570816);         //  4 MB
    unsigned* bc1  = (unsigned*)(wsb + 37765120);         //  4 MB
    float* scores  = (float*)   (wsb + 41959424);         // 16 KB
    float* wts     = (float*)   (wsb + 41975808);         // 16 KB
    float* ctx     = (float*)   (wsb + 41992192);         //  4 KB

    hipMemsetAsync(bc0, 0xFF, 2 * 4194304, stream);       // bc0+bc1 contiguous
    cvt_fp16<<<2048, 256, 0, stream>>>(w_hh0, wh0h, 4194304);
    cvt_fp16<<<2048, 256, 0, stream>>>(w_ih1, wi1h, 4194304);
    cvt_fp16<<<2048, 256, 0, stream>>>(w_hh1, wh1h, 4194304);
    bias_sum<<<16, 256, 0, stream>>>(b_ih1, b_hh1, b1s);

    dim3 gg(64, 16);
    gemm_xg_h<<<gg, 256, 0, stream>>>(x, w_ih0, b_ih0, b_hh0, xg0h, 1024, 4096, 1024);
    lstm_fused2<<<256, 256, 0, stream>>>(xg0h, wh0h, wi1h, wh1h, b1s,
                                         h0all, c0all, out1, hN, cN, bc0, bc1);
    attn_scores<<<1024, 256, 0, stream>>>(enc, hN + 1024, scores);
    attn_softmax<<<1, 1024, 0, stream>>>(scores, wts);
    attn_context<<<64, 256, 0, stream>>>(wts, enc, ctx);
    attn_final<<<256, 256, 0, stream>>>(ctx, hN + 1024, w_cat, b_cat, attn);
}